// Round 1
// baseline (4326.981 us; speedup 1.0000x reference)
//
#include <hip/hip_runtime.h>

#define NN 50000
#define NE 800000

// ---------------- degree / normalization ----------------
__global__ __launch_bounds__(256) void deg_init_k(float* __restrict__ deg) {
    int i = blockIdx.x * blockDim.x + threadIdx.x;
    if (i < NN) deg[i] = 1.0f;  // self-loop
}

__global__ __launch_bounds__(256) void deg_accum_k(const int* __restrict__ dst, float* __restrict__ deg) {
    int e = blockIdx.x * blockDim.x + threadIdx.x;
    if (e < NE) atomicAdd(&deg[dst[e]], 1.0f);
}

__global__ __launch_bounds__(256) void dinv_k(float* __restrict__ deg) {
    int i = blockIdx.x * blockDim.x + threadIdx.x;
    if (i < NN) deg[i] = rsqrtf(deg[i]);
}

// ---------------- propagation: out[d] += dinv[s]*dinv[d]*h[s] ----------------
// init kernel writes the self-loop term (dinv[i]^2 * h[i]) to every element,
// which doubles as the zero-init (d_ws is poisoned 0xAA before every launch).
template<int LOG2C4>
__global__ __launch_bounds__(256) void prop_init_k(const float4* __restrict__ h4,
                                                   float4* __restrict__ out4,
                                                   const float* __restrict__ dinv) {
    int i = blockIdx.x * blockDim.x + threadIdx.x;
    const int total = NN << LOG2C4;
    if (i >= total) return;
    int node = i >> LOG2C4;
    float w = dinv[node];
    w *= w;
    float4 v = h4[i];
    v.x *= w; v.y *= w; v.z *= w; v.w *= w;
    out4[i] = v;
}

template<int LOG2C4>
__global__ __launch_bounds__(256) void prop_edges_k(const float4* __restrict__ h4,
                                                    float* __restrict__ out,
                                                    const int* __restrict__ src,
                                                    const int* __restrict__ dst,
                                                    const float* __restrict__ dinv) {
    const int C4 = 1 << LOG2C4;
    unsigned tid = blockIdx.x * blockDim.x + threadIdx.x;
    unsigned e = tid >> LOG2C4;
    if (e >= NE) return;
    unsigned c4 = tid & (C4 - 1);
    int s = src[e], d = dst[e];
    float w = dinv[s] * dinv[d];
    float4 v = h4[((size_t)s << LOG2C4) + c4];
    float* op = out + ((((size_t)d << LOG2C4) + c4) << 2);
    atomicAdd(op + 0, v.x * w);
    atomicAdd(op + 1, v.y * w);
    atomicAdd(op + 2, v.z * w);
    atomicAdd(op + 3, v.w * w);
}

// ---------------- dual matmul + bias + relu ----------------
// out[n,j] = relu(A1[n,:] @ W1[:,j] + A2[n,:] @ W2[:,j] + b[j])
template<int K, int J, int NPB>
__global__ __launch_bounds__(J * NPB) void dual_mm_k(const float* __restrict__ A1,
                                                     const float* __restrict__ W1,
                                                     const float* __restrict__ A2,
                                                     const float* __restrict__ W2,
                                                     const float* __restrict__ b,
                                                     float* __restrict__ out, int n) {
    __shared__ float W1s[K * J];
    __shared__ float W2s[K * J];
    for (int i = threadIdx.x; i < K * J; i += J * NPB) {
        W1s[i] = W1[i];
        W2s[i] = W2[i];
    }
    __syncthreads();
    int tj = threadIdx.x % J;
    int tn = threadIdx.x / J;
    int node = blockIdx.x * NPB + tn;
    if (node >= n) return;
    const float4* a1 = (const float4*)(A1 + (size_t)node * K);
    const float4* a2 = (const float4*)(A2 + (size_t)node * K);
    float acc = b[tj];
#pragma unroll
    for (int k4 = 0; k4 < K / 4; k4++) {
        float4 v1 = a1[k4];
        float4 v2 = a2[k4];
        int k = k4 * 4;
        acc += v1.x * W1s[(k + 0) * J + tj] + v1.y * W1s[(k + 1) * J + tj] +
               v1.z * W1s[(k + 2) * J + tj] + v1.w * W1s[(k + 3) * J + tj];
        acc += v2.x * W2s[(k + 0) * J + tj] + v2.y * W2s[(k + 1) * J + tj] +
               v2.z * W2s[(k + 2) * J + tj] + v2.w * W2s[(k + 3) * J + tj];
    }
    out[(size_t)node * J + tj] = fmaxf(acc, 0.0f);
}

// ---------------- fused projection + coordinate heads ----------------
__global__ __launch_bounds__(256) void heads_k(const float* __restrict__ h2,
                                               const float* __restrict__ Wp1, const float* __restrict__ bp1,
                                               const float* __restrict__ Wp2, const float* __restrict__ bp2,
                                               const float* __restrict__ Wc1, const float* __restrict__ bc1,
                                               const float* __restrict__ Wc2, const float* __restrict__ bc2,
                                               float* __restrict__ coord, float* __restrict__ z, int n) {
    __shared__ float sWp1[32 * 32], sWp2[32 * 32], sWc1[32 * 16], sWc2[16 * 2];
    __shared__ float sbp1[32], sbp2[32], sbc1[16], sbc2[2];
    for (int i = threadIdx.x; i < 1024; i += 256) { sWp1[i] = Wp1[i]; sWp2[i] = Wp2[i]; }
    for (int i = threadIdx.x; i < 512; i += 256) sWc1[i] = Wc1[i];
    if (threadIdx.x < 32) {
        sWc2[threadIdx.x] = Wc2[threadIdx.x];
        sbp1[threadIdx.x] = bp1[threadIdx.x];
        sbp2[threadIdx.x] = bp2[threadIdx.x];
    }
    if (threadIdx.x < 16) sbc1[threadIdx.x] = bc1[threadIdx.x];
    if (threadIdx.x < 2) sbc2[threadIdx.x] = bc2[threadIdx.x];
    __syncthreads();
    int node = blockIdx.x * blockDim.x + threadIdx.x;
    if (node >= n) return;
    float h[32];
#pragma unroll
    for (int k = 0; k < 32; k++) h[k] = h2[(size_t)node * 32 + k];
    float t[32];
#pragma unroll
    for (int j = 0; j < 32; j++) {
        float s = sbp1[j];
#pragma unroll
        for (int k = 0; k < 32; k++) s += h[k] * sWp1[k * 32 + j];
        t[j] = fmaxf(s, 0.0f);
    }
#pragma unroll
    for (int j = 0; j < 32; j++) {
        float s = sbp2[j];
#pragma unroll
        for (int k = 0; k < 32; k++) s += t[k] * sWp2[k * 32 + j];
        z[(size_t)node * 32 + j] = s;
    }
    float tc[16];
#pragma unroll
    for (int j = 0; j < 16; j++) {
        float s = sbc1[j];
#pragma unroll
        for (int k = 0; k < 32; k++) s += h[k] * sWc1[k * 16 + j];
        tc[j] = fmaxf(s, 0.0f);
    }
#pragma unroll
    for (int j = 0; j < 2; j++) {
        float s = sbc2[j];
#pragma unroll
        for (int k = 0; k < 16; k++) s += tc[k] * sWc2[k * 2 + j];
        coord[(size_t)node * 2 + j] = s;
    }
}

extern "C" void kernel_launch(void* const* d_in, const int* in_sizes, int n_in,
                              void* d_out, int out_size, void* d_ws, size_t ws_size,
                              hipStream_t stream) {
    const float* x    = (const float*)d_in[0];
    const int*   ei   = (const int*)d_in[1];
    const int*   src  = ei;
    const int*   dst  = ei + NE;
    const float* W1_1 = (const float*)d_in[2];
    const float* W1_2 = (const float*)d_in[3];
    const float* b1   = (const float*)d_in[4];
    const float* W2_1 = (const float*)d_in[5];
    const float* W2_2 = (const float*)d_in[6];
    const float* b2   = (const float*)d_in[7];
    const float* Wp1  = (const float*)d_in[8];
    const float* bp1  = (const float*)d_in[9];
    const float* Wp2  = (const float*)d_in[10];
    const float* bp2  = (const float*)d_in[11];
    const float* Wc1  = (const float*)d_in[12];
    const float* bc1  = (const float*)d_in[13];
    const float* Wc2  = (const float*)d_in[14];
    const float* bc2  = (const float*)d_in[15];

    float* ws   = (float*)d_ws;
    float* dinv = ws;                          // NN
    float* bufA = dinv + NN;                   // NN*128
    float* bufB = bufA + (size_t)NN * 128;     // NN*128
    float* h1   = bufB + (size_t)NN * 128;     // NN*64
    float* bufC = bufA;                        // NN*64 (aliases bufA, layer-2)
    float* bufD = bufA + (size_t)NN * 64;      // NN*64
    float* h2   = bufB;                        // NN*32 (aliases bufB)

    float* coord = (float*)d_out;              // NN*2
    float* z     = (float*)d_out + 2 * NN;     // NN*32

    // 1) degrees -> dinv (in place)
    deg_init_k<<<(NN + 255) / 256, 256, 0, stream>>>(dinv);
    deg_accum_k<<<(NE + 255) / 256, 256, 0, stream>>>(dst, dinv);
    dinv_k<<<(NN + 255) / 256, 256, 0, stream>>>(dinv);

    // 2) bufA = A_hat @ x            (C=128, C4=32)
    prop_init_k<5><<<(NN * 32 + 255) / 256, 256, 0, stream>>>((const float4*)x, (float4*)bufA, dinv);
    prop_edges_k<5><<<(NE * 32 + 255) / 256, 256, 0, stream>>>((const float4*)x, bufA, src, dst, dinv);

    // 3) bufB = A_hat @ bufA
    prop_init_k<5><<<(NN * 32 + 255) / 256, 256, 0, stream>>>((const float4*)bufA, (float4*)bufB, dinv);
    prop_edges_k<5><<<(NE * 32 + 255) / 256, 256, 0, stream>>>((const float4*)bufA, bufB, src, dst, dinv);

    // 4) h1 = relu(bufA@W1_1 + bufB@W1_2 + b1)   K=128 J=64
    dual_mm_k<128, 64, 4><<<(NN + 3) / 4, 256, 0, stream>>>(bufA, W1_1, bufB, W1_2, b1, h1, NN);

    // 5) bufC = A_hat @ h1           (C=64, C4=16)
    prop_init_k<4><<<(NN * 16 + 255) / 256, 256, 0, stream>>>((const float4*)h1, (float4*)bufC, dinv);
    prop_edges_k<4><<<(NE * 16 + 255) / 256, 256, 0, stream>>>((const float4*)h1, bufC, src, dst, dinv);

    // 6) bufD = A_hat @ bufC
    prop_init_k<4><<<(NN * 16 + 255) / 256, 256, 0, stream>>>((const float4*)bufC, (float4*)bufD, dinv);
    prop_edges_k<4><<<(NE * 16 + 255) / 256, 256, 0, stream>>>((const float4*)bufC, bufD, src, dst, dinv);

    // 7) h2 = relu(bufC@W2_1 + bufD@W2_2 + b2)   K=64 J=32
    dual_mm_k<64, 32, 8><<<(NN + 7) / 8, 256, 0, stream>>>(bufC, W2_1, bufD, W2_2, b2, h2, NN);

    // 8) heads: z + coordinates
    heads_k<<<(NN + 255) / 256, 256, 0, stream>>>(h2, Wp1, bp1, Wp2, bp2, Wc1, bc1, Wc2, bc2, coord, z, NN);
}

// Round 2
// 698.760 us; speedup vs baseline: 6.1924x; 6.1924x over previous
//
#include <hip/hip_runtime.h>

#define NN 50000
#define NE 800000

// ---------------- CSR build ----------------
__global__ __launch_bounds__(256) void zero_cnt_k(int* __restrict__ cnt) {
    int i = blockIdx.x * blockDim.x + threadIdx.x;
    if (i < NN) cnt[i] = 0;
}

__global__ __launch_bounds__(256) void hist_k(const int* __restrict__ dst, int* __restrict__ cnt) {
    int e = blockIdx.x * blockDim.x + threadIdx.x;
    if (e < NE) atomicAdd(&cnt[dst[e]], 1);
}

__global__ __launch_bounds__(256) void dinv_k(const int* __restrict__ cnt, float* __restrict__ dinv) {
    int i = blockIdx.x * blockDim.x + threadIdx.x;
    if (i < NN) dinv[i] = rsqrtf((float)(cnt[i] + 1));  // +1 self loop
}

// single-block exclusive scan of cnt -> rowstart; zeroes cnt for reuse as cursor
#define SCAN_T 256
#define CHUNK ((NN + SCAN_T - 1) / SCAN_T)
__global__ __launch_bounds__(SCAN_T) void scan_k(const int* __restrict__ cnt_in,
                                                 int* __restrict__ cnt_zero,
                                                 int* __restrict__ rowstart) {
    __shared__ int sums[SCAN_T];
    int t = threadIdx.x;
    int base = t * CHUNK;
    int lim = min(base + CHUNK, NN);
    int s = 0;
    for (int i = base; i < lim; i++) s += cnt_in[i];
    sums[t] = s;
    __syncthreads();
    if (t == 0) {
        int run = 0;
        for (int i = 0; i < SCAN_T; i++) { int v = sums[i]; sums[i] = run; run += v; }
    }
    __syncthreads();
    int run = sums[t];
    for (int i = base; i < lim; i++) {
        rowstart[i] = run;
        run += cnt_in[i];
        cnt_zero[i] = 0;
    }
    if (t == SCAN_T - 1) rowstart[NN] = NE;
}

__global__ __launch_bounds__(256) void scatter_k(const int* __restrict__ src,
                                                 const int* __restrict__ dst,
                                                 const int* __restrict__ rowstart,
                                                 int* __restrict__ cursor,
                                                 const float* __restrict__ dinv,
                                                 int* __restrict__ col,
                                                 float* __restrict__ wgt) {
    int e = blockIdx.x * blockDim.x + threadIdx.x;
    if (e >= NE) return;
    int s = src[e], d = dst[e];
    int pos = rowstart[d] + atomicAdd(&cursor[d], 1);
    col[pos] = s;
    wgt[pos] = dinv[s] * dinv[d];
}

// ---------------- propagation (CSR, dst-stationary, no atomics) ----------------
// C4 threads per node, one float4 per thread. Self-loop folded into init.
template<int LOG2C4>
__global__ __launch_bounds__(256) void prop_csr_k(const float4* __restrict__ h4,
                                                  float4* __restrict__ out4,
                                                  const int* __restrict__ rowstart,
                                                  const int* __restrict__ col,
                                                  const float* __restrict__ wgt,
                                                  const float* __restrict__ dinv) {
    const int C4 = 1 << LOG2C4;
    unsigned tid = blockIdx.x * blockDim.x + threadIdx.x;
    unsigned node = tid >> LOG2C4;
    if (node >= NN) return;
    unsigned lane = tid & (C4 - 1);
    size_t rowoff = ((size_t)node << LOG2C4) + lane;
    float w0 = dinv[node];
    w0 *= w0;
    float4 acc = h4[rowoff];
    acc.x *= w0; acc.y *= w0; acc.z *= w0; acc.w *= w0;
    int rs = rowstart[node], re = rowstart[node + 1];
    for (int i = rs; i < re; i++) {
        int s = col[i];
        float w = wgt[i];
        float4 v = h4[((size_t)s << LOG2C4) + lane];
        acc.x += w * v.x;
        acc.y += w * v.y;
        acc.z += w * v.z;
        acc.w += w * v.w;
    }
    out4[rowoff] = acc;
}

// ---------------- dual matmul + bias + relu ----------------
template<int K, int J, int NPB>
__global__ __launch_bounds__(J * NPB) void dual_mm_k(const float* __restrict__ A1,
                                                     const float* __restrict__ W1,
                                                     const float* __restrict__ A2,
                                                     const float* __restrict__ W2,
                                                     const float* __restrict__ b,
                                                     float* __restrict__ out, int n) {
    __shared__ float W1s[K * J];
    __shared__ float W2s[K * J];
    for (int i = threadIdx.x; i < K * J; i += J * NPB) {
        W1s[i] = W1[i];
        W2s[i] = W2[i];
    }
    __syncthreads();
    int tj = threadIdx.x % J;
    int tn = threadIdx.x / J;
    int node = blockIdx.x * NPB + tn;
    if (node >= n) return;
    const float4* a1 = (const float4*)(A1 + (size_t)node * K);
    const float4* a2 = (const float4*)(A2 + (size_t)node * K);
    float acc = b[tj];
#pragma unroll
    for (int k4 = 0; k4 < K / 4; k4++) {
        float4 v1 = a1[k4];
        float4 v2 = a2[k4];
        int k = k4 * 4;
        acc += v1.x * W1s[(k + 0) * J + tj] + v1.y * W1s[(k + 1) * J + tj] +
               v1.z * W1s[(k + 2) * J + tj] + v1.w * W1s[(k + 3) * J + tj];
        acc += v2.x * W2s[(k + 0) * J + tj] + v2.y * W2s[(k + 1) * J + tj] +
               v2.z * W2s[(k + 2) * J + tj] + v2.w * W2s[(k + 3) * J + tj];
    }
    out[(size_t)node * J + tj] = fmaxf(acc, 0.0f);
}

// ---------------- fused projection + coordinate heads ----------------
__global__ __launch_bounds__(256) void heads_k(const float* __restrict__ h2,
                                               const float* __restrict__ Wp1, const float* __restrict__ bp1,
                                               const float* __restrict__ Wp2, const float* __restrict__ bp2,
                                               const float* __restrict__ Wc1, const float* __restrict__ bc1,
                                               const float* __restrict__ Wc2, const float* __restrict__ bc2,
                                               float* __restrict__ coord, float* __restrict__ z, int n) {
    __shared__ float sWp1[32 * 32], sWp2[32 * 32], sWc1[32 * 16], sWc2[16 * 2];
    __shared__ float sbp1[32], sbp2[32], sbc1[16], sbc2[2];
    for (int i = threadIdx.x; i < 1024; i += 256) { sWp1[i] = Wp1[i]; sWp2[i] = Wp2[i]; }
    for (int i = threadIdx.x; i < 512; i += 256) sWc1[i] = Wc1[i];
    if (threadIdx.x < 32) {
        sWc2[threadIdx.x] = Wc2[threadIdx.x];
        sbp1[threadIdx.x] = bp1[threadIdx.x];
        sbp2[threadIdx.x] = bp2[threadIdx.x];
    }
    if (threadIdx.x < 16) sbc1[threadIdx.x] = bc1[threadIdx.x];
    if (threadIdx.x < 2) sbc2[threadIdx.x] = bc2[threadIdx.x];
    __syncthreads();
    int node = blockIdx.x * blockDim.x + threadIdx.x;
    if (node >= n) return;
    float h[32];
#pragma unroll
    for (int k = 0; k < 32; k++) h[k] = h2[(size_t)node * 32 + k];
    float t[32];
#pragma unroll
    for (int j = 0; j < 32; j++) {
        float s = sbp1[j];
#pragma unroll
        for (int k = 0; k < 32; k++) s += h[k] * sWp1[k * 32 + j];
        t[j] = fmaxf(s, 0.0f);
    }
#pragma unroll
    for (int j = 0; j < 32; j++) {
        float s = sbp2[j];
#pragma unroll
        for (int k = 0; k < 32; k++) s += t[k] * sWp2[k * 32 + j];
        z[(size_t)node * 32 + j] = s;
    }
    float tc[16];
#pragma unroll
    for (int j = 0; j < 16; j++) {
        float s = sbc1[j];
#pragma unroll
        for (int k = 0; k < 32; k++) s += h[k] * sWc1[k * 16 + j];
        tc[j] = fmaxf(s, 0.0f);
    }
#pragma unroll
    for (int j = 0; j < 2; j++) {
        float s = sbc2[j];
#pragma unroll
        for (int k = 0; k < 16; k++) s += tc[k] * sWc2[k * 2 + j];
        coord[(size_t)node * 2 + j] = s;
    }
}

extern "C" void kernel_launch(void* const* d_in, const int* in_sizes, int n_in,
                              void* d_out, int out_size, void* d_ws, size_t ws_size,
                              hipStream_t stream) {
    const float* x    = (const float*)d_in[0];
    const int*   ei   = (const int*)d_in[1];
    const int*   src  = ei;
    const int*   dst  = ei + NE;
    const float* W1_1 = (const float*)d_in[2];
    const float* W1_2 = (const float*)d_in[3];
    const float* b1   = (const float*)d_in[4];
    const float* W2_1 = (const float*)d_in[5];
    const float* W2_2 = (const float*)d_in[6];
    const float* b2   = (const float*)d_in[7];
    const float* Wp1  = (const float*)d_in[8];
    const float* bp1  = (const float*)d_in[9];
    const float* Wp2  = (const float*)d_in[10];
    const float* bp2  = (const float*)d_in[11];
    const float* Wc1  = (const float*)d_in[12];
    const float* bc1  = (const float*)d_in[13];
    const float* Wc2  = (const float*)d_in[14];
    const float* bc2  = (const float*)d_in[15];

    // workspace layout
    float* ws    = (float*)d_ws;
    float* dinv  = ws;                              // NN
    int*   cnt   = (int*)(dinv + NN);               // NN   (histogram, then cursor)
    int*   rows  = cnt + NN;                        // NN+1
    int*   col   = rows + NN + 1;                   // NE
    float* wgt   = (float*)(col + NE);              // NE
    float* bufA  = wgt + NE;                        // NN*128
    float* bufB  = bufA + (size_t)NN * 128;         // NN*128
    float* h1    = bufB + (size_t)NN * 128;         // NN*64
    float* bufC  = bufA;                            // NN*64 (aliases bufA, layer-2)
    float* bufD  = bufA + (size_t)NN * 64;          // NN*64
    float* h2    = bufB;                            // NN*32 (aliases bufB)

    float* coord = (float*)d_out;                   // NN*2
    float* z     = (float*)d_out + 2 * NN;          // NN*32

    // 1) CSR build + dinv
    zero_cnt_k<<<(NN + 255) / 256, 256, 0, stream>>>(cnt);
    hist_k<<<(NE + 255) / 256, 256, 0, stream>>>(dst, cnt);
    dinv_k<<<(NN + 255) / 256, 256, 0, stream>>>(cnt, dinv);
    scan_k<<<1, SCAN_T, 0, stream>>>(cnt, cnt, rows);
    scatter_k<<<(NE + 255) / 256, 256, 0, stream>>>(src, dst, rows, cnt, dinv, col, wgt);

    // 2) bufA = A_hat @ x            (C=128, C4=32)
    prop_csr_k<5><<<(NN * 32 + 255) / 256, 256, 0, stream>>>((const float4*)x, (float4*)bufA, rows, col, wgt, dinv);
    // 3) bufB = A_hat @ bufA
    prop_csr_k<5><<<(NN * 32 + 255) / 256, 256, 0, stream>>>((const float4*)bufA, (float4*)bufB, rows, col, wgt, dinv);
    // 4) h1 = relu(bufA@W1_1 + bufB@W1_2 + b1)   K=128 J=64
    dual_mm_k<128, 64, 4><<<(NN + 3) / 4, 256, 0, stream>>>(bufA, W1_1, bufB, W1_2, b1, h1, NN);
    // 5) bufC = A_hat @ h1           (C=64, C4=16)
    prop_csr_k<4><<<(NN * 16 + 255) / 256, 256, 0, stream>>>((const float4*)h1, (float4*)bufC, rows, col, wgt, dinv);
    // 6) bufD = A_hat @ bufC
    prop_csr_k<4><<<(NN * 16 + 255) / 256, 256, 0, stream>>>((const float4*)bufC, (float4*)bufD, rows, col, wgt, dinv);
    // 7) h2 = relu(bufC@W2_1 + bufD@W2_2 + b2)   K=64 J=32
    dual_mm_k<64, 32, 8><<<(NN + 7) / 8, 256, 0, stream>>>(bufC, W2_1, bufD, W2_2, b2, h2, NN);
    // 8) heads
    heads_k<<<(NN + 255) / 256, 256, 0, stream>>>(h2, Wp1, bp1, Wp2, bp2, Wc1, bc1, Wc2, bc2, coord, z, NN);
}